// Round 1
// baseline (6558.011 us; speedup 1.0000x reference)
//
#include <hip/hip_runtime.h>
#include <math.h>

// ---------------- problem constants ----------------
#define CC    512
#define TSZ   16
#define WHN   196
#define DH    64
#define TK    14
#define NB    12544   // HEADS*B*WHN = 8*8*196
#define NS    896     // HEADS*B*TK  = 8*8*14
#define MPROJ 25088   // 3136*8
#define MOUT  21952   // 2744*8

#define SZ_T  12845056ull   // NB*16*64
#define SZ_S  11239424ull   // NS*196*64

#define OUT0_SZ   11243520ull   // 2745*8*512
#define ATTN_SZ   34420736ull   // 896*196*196

// ---------------- K0: copy cls row ----------------
__global__ void k0_cls(const float* __restrict__ q, float* __restrict__ out) {
  int i = blockIdx.x * 256 + threadIdx.x;   // 1024 float4 = 4096 floats
  ((float4*)out)[i] = ((const float4*)q)[i];
}

// ---------------- K1: QKV projection (f32 GEMM, scatter to temporal) ----------------
// C[m][n] = sum_k A[m][k]*W[n][k] + bias[n];  A = q+4096 (ld 512), M=25088, N=1536, K=512
// scatter: part=n/512 -> QT/KT/VT; [nb][t][d] with nb=((head*8+b)*196+wh)
__global__ __launch_bounds__(256) void k1_qkv(
    const float* __restrict__ q, const float* __restrict__ W,
    const float* __restrict__ bias,
    float* __restrict__ QT, float* __restrict__ KT, float* __restrict__ VT)
{
  __shared__ float As[16][132];   // [k][m], row 528B (16B aligned)
  __shared__ float Bs[16][68];    // [k][n]
  const int tid = threadIdx.x;
  const int tx = tid & 15;        // n quad
  const int ty = tid >> 4;        // m octet
  const int m0 = blockIdx.x * 128;
  const int n0 = blockIdx.y * 64;
  const float* __restrict__ A = q + 4096;

  float acc[8][4];
#pragma unroll
  for (int i = 0; i < 8; ++i)
#pragma unroll
    for (int j = 0; j < 4; ++j) acc[i][j] = 0.f;

  for (int k0 = 0; k0 < 512; k0 += 16) {
#pragma unroll
    for (int r = 0; r < 2; ++r) {
      int e = tid + r * 256;
      int m = e >> 2, kq = e & 3;
      const float4 a4 = *(const float4*)&A[(size_t)(m0 + m) * 512 + k0 + kq * 4];
      As[kq*4+0][m] = a4.x; As[kq*4+1][m] = a4.y;
      As[kq*4+2][m] = a4.z; As[kq*4+3][m] = a4.w;
    }
    {
      int n = tid >> 2, kq = tid & 3;
      const float4 b4 = *(const float4*)&W[(size_t)(n0 + n) * 512 + k0 + kq * 4];
      Bs[kq*4+0][n] = b4.x; Bs[kq*4+1][n] = b4.y;
      Bs[kq*4+2][n] = b4.z; Bs[kq*4+3][n] = b4.w;
    }
    __syncthreads();
#pragma unroll
    for (int kk = 0; kk < 16; ++kk) {
      const float4 a0 = *(const float4*)&As[kk][ty*8];
      const float4 a1 = *(const float4*)&As[kk][ty*8+4];
      const float4 b  = *(const float4*)&Bs[kk][tx*4];
      float am[8] = {a0.x,a0.y,a0.z,a0.w,a1.x,a1.y,a1.z,a1.w};
#pragma unroll
      for (int i = 0; i < 8; ++i) {
        acc[i][0] += am[i]*b.x; acc[i][1] += am[i]*b.y;
        acc[i][2] += am[i]*b.z; acc[i][3] += am[i]*b.w;
      }
    }
    __syncthreads();
  }

  const int part = n0 >> 9;
  const int head = (n0 & 511) >> 6;
  float* __restrict__ dst = (part == 0) ? QT : (part == 1) ? KT : VT;
  const float b0 = bias[n0 + tx*4 + 0];
  const float b1 = bias[n0 + tx*4 + 1];
  const float b2 = bias[n0 + tx*4 + 2];
  const float b3 = bias[n0 + tx*4 + 3];
#pragma unroll
  for (int i = 0; i < 8; ++i) {
    int m = m0 + ty*8 + i;
    int s = m >> 3, b = m & 7;
    int t_idx = s / 196, wh = s % 196;
    size_t off = ((size_t)((head*8 + b)*196 + wh) * 16 + t_idx) * 64 + tx*4;
    float4 v = make_float4(acc[i][0]+b0, acc[i][1]+b1, acc[i][2]+b2, acc[i][3]+b3);
    *(float4*)&dst[off] = v;
  }
}

// ---------------- K2: temporal attention + std + top-14 + re-softmax + PV ----------------
// one 64-thread block per nb
__global__ __launch_bounds__(64) void k2_temporal(
    const float* __restrict__ QT, const float* __restrict__ KT,
    const float* __restrict__ VT,
    float* __restrict__ VSo, int* __restrict__ IDXW, float* __restrict__ idxOut)
{
  const int nb = blockIdx.x;
  const int lane = threadIdx.x;
  __shared__ float Q[16][72], K[16][72], V[16][72];
  __shared__ float S[16][17], Aa[16][17], P[14][17];
  __shared__ float stdv[16];
  __shared__ int drop[2];

  // stage Q,K,V tiles [16][64]
#pragma unroll
  for (int r = 0; r < 4; ++r) {
    int e = lane + 64*r;          // 0..255
    int i = e >> 4, d4 = e & 15;
    size_t g = ((size_t)nb*16 + i)*64 + d4*4;
    *(float4*)&Q[i][d4*4] = *(const float4*)&QT[g];
    *(float4*)&K[i][d4*4] = *(const float4*)&KT[g];
    *(float4*)&V[i][d4*4] = *(const float4*)&VT[g];
  }
  __syncthreads();

  // S[i][j] = q_i . k_j / 8 ; each lane: 4 entries (same i, 4 consecutive j)
  {
    const int i = lane >> 2;
    const int jb = (lane & 3) * 4;
    float acc[4] = {0.f,0.f,0.f,0.f};
#pragma unroll
    for (int d4 = 0; d4 < 16; ++d4) {
      const float4 q4 = *(const float4*)&Q[i][d4*4];
#pragma unroll
      for (int r = 0; r < 4; ++r) {
        const float4 k4 = *(const float4*)&K[jb + r][d4*4];
        acc[r] += q4.x*k4.x + q4.y*k4.y + q4.z*k4.z + q4.w*k4.w;
      }
    }
#pragma unroll
    for (int r = 0; r < 4; ++r) S[i][jb+r] = acc[r] * 0.125f;
  }
  __syncthreads();

  // per-row softmax + std (ddof=1), lanes 0..15
  if (lane < 16) {
    float mx = S[lane][0];
#pragma unroll
    for (int j = 1; j < 16; ++j) mx = fmaxf(mx, S[lane][j]);
    float sum = 0.f;
#pragma unroll
    for (int j = 0; j < 16; ++j) { float e = expf(S[lane][j] - mx); Aa[lane][j] = e; sum += e; }
    float inv = 1.f / sum;
    float msum = 0.f;
#pragma unroll
    for (int j = 0; j < 16; ++j) { float a = Aa[lane][j] * inv; Aa[lane][j] = a; msum += a; }
    float mean = msum * 0.0625f;
    float var = 0.f;
#pragma unroll
    for (int j = 0; j < 16; ++j) { float d = Aa[lane][j] - mean; var += d*d; }
    stdv[lane] = sqrtf(var * (1.f/15.f));
  }
  __syncthreads();

  // drop the 2 worst rows: order (std asc, index desc) — matches top_k keep-(desc,idx asc)
  if (lane == 0) {
    int w0 = 0;
    for (int i = 1; i < 16; ++i)
      if (stdv[i] < stdv[w0] || (stdv[i] == stdv[w0] && i > w0)) w0 = i;
    int w1 = (w0 == 0) ? 1 : 0;
    for (int i = 0; i < 16; ++i) {
      if (i == w0) continue;
      if (stdv[i] < stdv[w1] || (stdv[i] == stdv[w1] && i > w1)) w1 = i;
    }
    drop[0] = min(w0, w1); drop[1] = max(w0, w1);
  }
  __syncthreads();
  const int dmin = drop[0], dmax = drop[1];

  // kept index + attn2 (softmax of pooled attn rows), lanes 0..13
  if (lane < 14) {
    int v = lane;
    if (v >= dmin) v++;
    if (v >= dmax) v++;
    IDXW[(size_t)nb*14 + lane] = v;
    idxOut[(size_t)nb*14 + lane] = (float)v;
    float mx = Aa[v][0];
#pragma unroll
    for (int j = 1; j < 16; ++j) mx = fmaxf(mx, Aa[v][j]);
    float sum = 0.f;
#pragma unroll
    for (int j = 0; j < 16; ++j) { float e = expf(Aa[v][j] - mx); P[lane][j] = e; sum += e; }
    float inv = 1.f / sum;
#pragma unroll
    for (int j = 0; j < 16; ++j) P[lane][j] *= inv;
  }
  __syncthreads();

  // output_t = attn2 @ v_t, written directly in spatial (v_s) layout
  const int hb = nb / 196, wh = nb % 196;
#pragma unroll
  for (int r = 0; r < 14; ++r) {
    float acc = 0.f;
#pragma unroll
    for (int j = 0; j < 16; ++j) acc += P[r][j] * V[j][lane];
    VSo[(((size_t)hb*14 + r)*196 + wh)*64 + lane] = acc;
  }
}

// ---------------- K3: spatial attention ----------------
// block = (ns, i-tile of 32 q-rows); 256 threads; grid 896*7
__global__ __launch_bounds__(256) void k3_spatial(
    const float* __restrict__ QT, const float* __restrict__ KT,
    const float* __restrict__ VS, const int* __restrict__ IDXW,
    float* __restrict__ attnOut, float* __restrict__ OS)
{
  const int bid = blockIdx.x;
  const int ns = bid / 7, it = bid % 7;
  const int hb = ns / 14, tp = ns % 14;
  const int qi0 = it * 32;
  const int vr = min(32, 196 - qi0);
  const int tid = threadIdx.x;
  const int lane = tid & 63;
  const int w = tid >> 6;

  __shared__ float Qs[32][64];     // broadcast-only access
  __shared__ float KV[64*65];      // K^T [d][jl] stride 65 ; reused as V [jl][d] stride 64
  __shared__ float Ss[32][200];

  // stage gathered Q rows
  for (int e = tid; e < 32*64; e += 256) {
    int i = e >> 6, d = e & 63;
    float val = 0.f;
    if (i < vr) {
      int nb = hb*196 + qi0 + i;
      int tt = IDXW[(size_t)nb*14 + tp];
      val = QT[((size_t)nb*16 + tt)*64 + d];
    }
    Qs[i][d] = val;
  }

  float oacc[8];
#pragma unroll
  for (int k = 0; k < 8; ++k) oacc[k] = 0.f;

  // ---- QK^T /8 over 4 j-tiles ----
  for (int jt = 0; jt < 4; ++jt) {
    const int j0 = jt * 64;
    const int jn = min(64, 196 - j0);
    __syncthreads();
    for (int e4 = tid; e4 < jn*16; e4 += 256) {
      int jl = e4 >> 4, d4 = e4 & 15;
      int nb = hb*196 + j0 + jl;
      int tt = IDXW[(size_t)nb*14 + tp];
      const float4 k4 = *(const float4*)&KT[((size_t)nb*16 + tt)*64 + d4*4];
      KV[(d4*4+0)*65 + jl] = k4.x; KV[(d4*4+1)*65 + jl] = k4.y;
      KV[(d4*4+2)*65 + jl] = k4.z; KV[(d4*4+3)*65 + jl] = k4.w;
    }
    __syncthreads();
    float sacc[8];
#pragma unroll
    for (int k = 0; k < 8; ++k) sacc[k] = 0.f;
#pragma unroll
    for (int d4 = 0; d4 < 16; ++d4) {
      const float kv0 = KV[(d4*4+0)*65 + lane];
      const float kv1 = KV[(d4*4+1)*65 + lane];
      const float kv2 = KV[(d4*4+2)*65 + lane];
      const float kv3 = KV[(d4*4+3)*65 + lane];
#pragma unroll
      for (int k = 0; k < 8; ++k) {
        const float4 q4 = *(const float4*)&Qs[w*8+k][d4*4];
        sacc[k] += q4.x*kv0 + q4.y*kv1 + q4.z*kv2 + q4.w*kv3;
      }
    }
    if (lane < jn) {
#pragma unroll
      for (int k = 0; k < 8; ++k) Ss[w*8+k][j0 + lane] = sacc[k] * 0.125f;
    }
  }
  __syncthreads();

  // ---- row softmax (8 threads per row) ----
  {
    const int r = tid >> 3, sub = tid & 7;
    float mx = -1e30f;
    for (int j = sub; j < 196; j += 8) mx = fmaxf(mx, Ss[r][j]);
    mx = fmaxf(mx, __shfl_xor(mx, 1));
    mx = fmaxf(mx, __shfl_xor(mx, 2));
    mx = fmaxf(mx, __shfl_xor(mx, 4));
    float sum = 0.f;
    for (int j = sub; j < 196; j += 8) { float e = __expf(Ss[r][j] - mx); Ss[r][j] = e; sum += e; }
    sum += __shfl_xor(sum, 1);
    sum += __shfl_xor(sum, 2);
    sum += __shfl_xor(sum, 4);
    float inv = 1.f / sum;
    for (int j = sub; j < 196; j += 8) Ss[r][j] *= inv;
  }
  __syncthreads();

  // write attn_s (output)
  for (int e = tid; e < vr*196; e += 256) {
    int i = e / 196, j = e % 196;
    attnOut[((size_t)ns*196 + qi0 + i)*196 + j] = Ss[i][j];
  }

  // ---- PV ----
  for (int jt = 0; jt < 4; ++jt) {
    const int j0 = jt * 64;
    const int jn = min(64, 196 - j0);
    __syncthreads();
    for (int e4 = tid; e4 < jn*16; e4 += 256) {
      int jl = e4 >> 4, d4 = e4 & 15;
      *(float4*)&KV[jl*64 + d4*4] =
          *(const float4*)&VS[((size_t)ns*196 + j0 + jl)*64 + d4*4];
    }
    __syncthreads();
    const int jn4 = jn >> 2;
    for (int q4i = 0; q4i < jn4; ++q4i) {
      const float v0 = KV[(q4i*4+0)*64 + lane];
      const float v1 = KV[(q4i*4+1)*64 + lane];
      const float v2 = KV[(q4i*4+2)*64 + lane];
      const float v3 = KV[(q4i*4+3)*64 + lane];
#pragma unroll
      for (int k = 0; k < 8; ++k) {
        const float4 s4 = *(const float4*)&Ss[w*8+k][j0 + q4i*4];
        oacc[k] += s4.x*v0 + s4.y*v1 + s4.z*v2 + s4.w*v3;
      }
    }
  }
#pragma unroll
  for (int k = 0; k < 8; ++k) {
    int i = w*8 + k;
    if (i < vr) OS[((size_t)ns*196 + qi0 + i)*64 + lane] = oacc[k];
  }
}

// ---------------- K4: out projection ----------------
// out[1+row][b][n] = sum_k OS_gathered[m][k]*Wo[n][k] + bo[n];  M=21952, N=512, K=512
__global__ __launch_bounds__(256) void k4_outproj(
    const float* __restrict__ OS, const float* __restrict__ Wo,
    const float* __restrict__ bo, float* __restrict__ out)
{
  __shared__ float As[16][132];
  __shared__ float Bs[16][68];
  const int tid = threadIdx.x;
  const int tx = tid & 15;
  const int ty = tid >> 4;
  const int m0 = blockIdx.x * 128;
  const int n0 = blockIdx.y * 64;

  float acc[8][4];
#pragma unroll
  for (int i = 0; i < 8; ++i)
#pragma unroll
    for (int j = 0; j < 4; ++j) acc[i][j] = 0.f;

  for (int k0 = 0; k0 < 512; k0 += 16) {
    const int head = k0 >> 6;   // k-tile of 16 stays within one head block
#pragma unroll
    for (int r = 0; r < 2; ++r) {
      int e = tid + r * 256;
      int m = e >> 2, kq = e & 3;
      int mm = m0 + m;
      float4 a4 = make_float4(0.f,0.f,0.f,0.f);
      if (mm < MOUT) {
        int t1 = mm / 1568; int r1 = mm - t1*1568;
        int wh = r1 >> 3;    int b  = r1 & 7;
        int d = (k0 & 63) + kq*4;
        a4 = *(const float4*)&OS[((((size_t)(head*8 + b)*14) + t1)*196 + wh)*64 + d];
      }
      As[kq*4+0][m] = a4.x; As[kq*4+1][m] = a4.y;
      As[kq*4+2][m] = a4.z; As[kq*4+3][m] = a4.w;
    }
    {
      int n = tid >> 2, kq = tid & 3;
      const float4 b4 = *(const float4*)&Wo[(size_t)(n0 + n) * 512 + k0 + kq * 4];
      Bs[kq*4+0][n] = b4.x; Bs[kq*4+1][n] = b4.y;
      Bs[kq*4+2][n] = b4.z; Bs[kq*4+3][n] = b4.w;
    }
    __syncthreads();
#pragma unroll
    for (int kk = 0; kk < 16; ++kk) {
      const float4 a0 = *(const float4*)&As[kk][ty*8];
      const float4 a1 = *(const float4*)&As[kk][ty*8+4];
      const float4 b  = *(const float4*)&Bs[kk][tx*4];
      float am[8] = {a0.x,a0.y,a0.z,a0.w,a1.x,a1.y,a1.z,a1.w};
#pragma unroll
      for (int i = 0; i < 8; ++i) {
        acc[i][0] += am[i]*b.x; acc[i][1] += am[i]*b.y;
        acc[i][2] += am[i]*b.z; acc[i][3] += am[i]*b.w;
      }
    }
    __syncthreads();
  }

  const float b0 = bo[n0 + tx*4 + 0];
  const float b1 = bo[n0 + tx*4 + 1];
  const float b2 = bo[n0 + tx*4 + 2];
  const float b3 = bo[n0 + tx*4 + 3];
#pragma unroll
  for (int i = 0; i < 8; ++i) {
    int mm = m0 + ty*8 + i;
    if (mm < MOUT) {
      size_t off = 4096 + (size_t)(mm >> 3)*4096 + (size_t)(mm & 7)*512 + n0 + tx*4;
      float4 v = make_float4(acc[i][0]+b0, acc[i][1]+b1, acc[i][2]+b2, acc[i][3]+b3);
      *(float4*)&out[off] = v;
    }
  }
}

// ---------------- launch ----------------
extern "C" void kernel_launch(void* const* d_in, const int* in_sizes, int n_in,
                              void* d_out, int out_size, void* d_ws, size_t ws_size,
                              hipStream_t stream) {
  const float* q  = (const float*)d_in[0];
  // d_in[1] (k) and d_in[2] (value) are unused by the reference
  const float* Wi = (const float*)d_in[3];
  const float* bi = (const float*)d_in[4];
  const float* Wo = (const float*)d_in[5];
  const float* bo = (const float*)d_in[6];

  float* out     = (float*)d_out;
  float* attnOut = out + OUT0_SZ;
  float* idxOut  = out + OUT0_SZ + ATTN_SZ;

  float* ws = (float*)d_ws;
  float* QT = ws;
  float* KT = QT + SZ_T;
  float* VT = KT + SZ_T;
  float* VS = VT + SZ_T;
  float* OS = VS + SZ_S;
  int* IDXW = (int*)(OS + SZ_S);
  // total ws use: 3*SZ_T + 2*SZ_S + NB*TK ints ≈ 233.6 MiB

  k0_cls<<<4, 256, 0, stream>>>(q, out);
  k1_qkv<<<dim3(196, 24), 256, 0, stream>>>(q, Wi, bi, QT, KT, VT);
  k2_temporal<<<NB, 64, 0, stream>>>(QT, KT, VT, VS, IDXW, idxOut);
  k3_spatial<<<NS * 7, 256, 0, stream>>>(QT, KT, VS, IDXW, attnOut, OS);
  k4_outproj<<<dim3(172, 8), 256, 0, stream>>>(OS, Wo, bo, out);
}

// Round 3
// 1019.466 us; speedup vs baseline: 6.4328x; 6.4328x over previous
//
#include <hip/hip_runtime.h>
#include <math.h>

// ---------------- problem constants ----------------
#define CC    512
#define TSZ   16
#define WHN   196
#define DH    64
#define TK    14
#define NB    12544   // HEADS*B*WHN = 8*8*196
#define NS    896     // HEADS*B*TK  = 8*8*14
#define MPROJ 25088   // 3136*8
#define MOUT  21952   // 2744*8

#define SZ_T  12845056ull   // NB*16*64
#define SZ_S  11239424ull   // NS*196*64

#define OUT0_SZ   11243520ull   // 2745*8*512
#define ATTN_SZ   34420736ull   // 896*196*196

typedef __bf16 v8bf  __attribute__((ext_vector_type(8)));
typedef __bf16 v4bf  __attribute__((ext_vector_type(4)));
typedef float  f32x4 __attribute__((ext_vector_type(4)));

// ---------------- K0: copy cls row ----------------
__global__ void k0_cls(const float* __restrict__ q, float* __restrict__ out) {
  int i = blockIdx.x * 256 + threadIdx.x;   // 1024 float4 = 4096 floats
  ((float4*)out)[i] = ((const float4*)q)[i];
}

// ---------------- K1: QKV projection (f32 GEMM, scatter to temporal) ----------------
__global__ __launch_bounds__(256) void k1_qkv(
    const float* __restrict__ q, const float* __restrict__ W,
    const float* __restrict__ bias,
    float* __restrict__ QT, float* __restrict__ KT, float* __restrict__ VT)
{
  __shared__ float As[16][132];   // [k][m]
  __shared__ float Bs[16][68];    // [k][n]
  const int tid = threadIdx.x;
  const int tx = tid & 15;
  const int ty = tid >> 4;
  const int m0 = blockIdx.x * 128;
  const int n0 = blockIdx.y * 64;
  const float* __restrict__ A = q + 4096;

  float acc[8][4];
#pragma unroll
  for (int i = 0; i < 8; ++i)
#pragma unroll
    for (int j = 0; j < 4; ++j) acc[i][j] = 0.f;

  for (int k0 = 0; k0 < 512; k0 += 16) {
#pragma unroll
    for (int r = 0; r < 2; ++r) {
      int e = tid + r * 256;
      int m = e >> 2, kq = e & 3;
      const float4 a4 = *(const float4*)&A[(size_t)(m0 + m) * 512 + k0 + kq * 4];
      As[kq*4+0][m] = a4.x; As[kq*4+1][m] = a4.y;
      As[kq*4+2][m] = a4.z; As[kq*4+3][m] = a4.w;
    }
    {
      int n = tid >> 2, kq = tid & 3;
      const float4 b4 = *(const float4*)&W[(size_t)(n0 + n) * 512 + k0 + kq * 4];
      Bs[kq*4+0][n] = b4.x; Bs[kq*4+1][n] = b4.y;
      Bs[kq*4+2][n] = b4.z; Bs[kq*4+3][n] = b4.w;
    }
    __syncthreads();
#pragma unroll
    for (int kk = 0; kk < 16; ++kk) {
      const float4 a0 = *(const float4*)&As[kk][ty*8];
      const float4 a1 = *(const float4*)&As[kk][ty*8+4];
      const float4 b  = *(const float4*)&Bs[kk][tx*4];
      float am[8] = {a0.x,a0.y,a0.z,a0.w,a1.x,a1.y,a1.z,a1.w};
#pragma unroll
      for (int i = 0; i < 8; ++i) {
        acc[i][0] += am[i]*b.x; acc[i][1] += am[i]*b.y;
        acc[i][2] += am[i]*b.z; acc[i][3] += am[i]*b.w;
      }
    }
    __syncthreads();
  }

  const int part = n0 >> 9;
  const int head = (n0 & 511) >> 6;
  float* __restrict__ dst = (part == 0) ? QT : (part == 1) ? KT : VT;
  const float b0 = bias[n0 + tx*4 + 0];
  const float b1 = bias[n0 + tx*4 + 1];
  const float b2 = bias[n0 + tx*4 + 2];
  const float b3 = bias[n0 + tx*4 + 3];
#pragma unroll
  for (int i = 0; i < 8; ++i) {
    int m = m0 + ty*8 + i;
    int s = m >> 3, b = m & 7;
    int t_idx = s / 196, wh = s % 196;
    size_t off = ((size_t)((head*8 + b)*196 + wh) * 16 + t_idx) * 64 + tx*4;
    float4 v = make_float4(acc[i][0]+b0, acc[i][1]+b1, acc[i][2]+b2, acc[i][3]+b3);
    *(float4*)&dst[off] = v;
  }
}

// ---------------- K2: temporal attention + std + top-14 + re-softmax + PV ----------------
__global__ __launch_bounds__(64) void k2_temporal(
    const float* __restrict__ QT, const float* __restrict__ KT,
    const float* __restrict__ VT,
    float* __restrict__ VSo, int* __restrict__ IDXW, float* __restrict__ idxOut)
{
  const int nb = blockIdx.x;
  const int lane = threadIdx.x;
  __shared__ float Q[16][72], K[16][72], V[16][72];
  __shared__ float S[16][17], Aa[16][17], P[14][17];
  __shared__ float stdv[16];
  __shared__ int drop[2];

#pragma unroll
  for (int r = 0; r < 4; ++r) {
    int e = lane + 64*r;
    int i = e >> 4, d4 = e & 15;
    size_t g = ((size_t)nb*16 + i)*64 + d4*4;
    *(float4*)&Q[i][d4*4] = *(const float4*)&QT[g];
    *(float4*)&K[i][d4*4] = *(const float4*)&KT[g];
    *(float4*)&V[i][d4*4] = *(const float4*)&VT[g];
  }
  __syncthreads();

  {
    const int i = lane >> 2;
    const int jb = (lane & 3) * 4;
    float acc[4] = {0.f,0.f,0.f,0.f};
#pragma unroll
    for (int d4 = 0; d4 < 16; ++d4) {
      const float4 q4 = *(const float4*)&Q[i][d4*4];
#pragma unroll
      for (int r = 0; r < 4; ++r) {
        const float4 k4 = *(const float4*)&K[jb + r][d4*4];
        acc[r] += q4.x*k4.x + q4.y*k4.y + q4.z*k4.z + q4.w*k4.w;
      }
    }
#pragma unroll
    for (int r = 0; r < 4; ++r) S[i][jb+r] = acc[r] * 0.125f;
  }
  __syncthreads();

  if (lane < 16) {
    float mx = S[lane][0];
#pragma unroll
    for (int j = 1; j < 16; ++j) mx = fmaxf(mx, S[lane][j]);
    float sum = 0.f;
#pragma unroll
    for (int j = 0; j < 16; ++j) { float e = expf(S[lane][j] - mx); Aa[lane][j] = e; sum += e; }
    float inv = 1.f / sum;
    float msum = 0.f;
#pragma unroll
    for (int j = 0; j < 16; ++j) { float a = Aa[lane][j] * inv; Aa[lane][j] = a; msum += a; }
    float mean = msum * 0.0625f;
    float var = 0.f;
#pragma unroll
    for (int j = 0; j < 16; ++j) { float d = Aa[lane][j] - mean; var += d*d; }
    stdv[lane] = sqrtf(var * (1.f/15.f));
  }
  __syncthreads();

  if (lane == 0) {
    int w0 = 0;
    for (int i = 1; i < 16; ++i)
      if (stdv[i] < stdv[w0] || (stdv[i] == stdv[w0] && i > w0)) w0 = i;
    int w1 = (w0 == 0) ? 1 : 0;
    for (int i = 0; i < 16; ++i) {
      if (i == w0) continue;
      if (stdv[i] < stdv[w1] || (stdv[i] == stdv[w1] && i > w1)) w1 = i;
    }
    drop[0] = min(w0, w1); drop[1] = max(w0, w1);
  }
  __syncthreads();
  const int dmin = drop[0], dmax = drop[1];

  if (lane < 14) {
    int v = lane;
    if (v >= dmin) v++;
    if (v >= dmax) v++;
    IDXW[(size_t)nb*14 + lane] = v;
    idxOut[(size_t)nb*14 + lane] = (float)v;
    float mx = Aa[v][0];
#pragma unroll
    for (int j = 1; j < 16; ++j) mx = fmaxf(mx, Aa[v][j]);
    float sum = 0.f;
#pragma unroll
    for (int j = 0; j < 16; ++j) { float e = expf(Aa[v][j] - mx); P[lane][j] = e; sum += e; }
    float inv = 1.f / sum;
#pragma unroll
    for (int j = 0; j < 16; ++j) P[lane][j] *= inv;
  }
  __syncthreads();

  const int hb = nb / 196, wh = nb % 196;
#pragma unroll
  for (int r = 0; r < 14; ++r) {
    float acc = 0.f;
#pragma unroll
    for (int j = 0; j < 16; ++j) acc += P[r][j] * V[j][lane];
    VSo[(((size_t)hb*14 + r)*196 + wh)*64 + lane] = acc;
  }
}

// ---------------- K3: spatial attention, bf16 MFMA, fused QK+softmax+PV ----------------
// one block (256 thr, 4 waves) per ns. Wave w handles M-tiles {w, w+4, w+8, w+12}.
// LDS: K rows [208][64] bf16 (slot-swizzled), V^T [64][256] bf16 (slot-swizzled),
//      per-wave P tile [16][32] bf16, TT[208] gathered t-indices.
__global__ __launch_bounds__(256) void k3_spatial(
    const float* __restrict__ QT, const float* __restrict__ KT,
    const float* __restrict__ VS, const int* __restrict__ IDXW,
    float* __restrict__ attnOut, float* __restrict__ OS)
{
  __shared__ __bf16 Klds[208*64];   // row j: 8 slots of 16B, slot ^= (j&7)
  __shared__ __bf16 Vt[64*256];     // row d: 32 slots of 16B (28 used), slot ^= (d&7)
  __shared__ __bf16 Plds[4*16*32];  // per-wave [16][32], slot ^= (row&3)
  __shared__ int    TT[208];

  const int ns = blockIdx.x;
  const int hb = ns / 14, tp = ns % 14;
  const int tid = threadIdx.x;
  const int lane = tid & 63;
  const int wid = tid >> 6;
  const int g = lane >> 4;
  const int col = lane & 15;

  if (tid < 208)
    TT[tid] = (tid < 196) ? IDXW[(size_t)(hb*196 + tid)*14 + tp] : 0;
  __syncthreads();

  // stage K (gathered rows, f32 -> bf16, swizzled)
  for (int e = tid; e < 208*16; e += 256) {
    int jl = e >> 4, d4 = e & 15;
    float4 k4 = make_float4(0.f,0.f,0.f,0.f);
    if (jl < 196) {
      int nb = hb*196 + jl;
      k4 = *(const float4*)&KT[((size_t)nb*16 + TT[jl])*64 + d4*4];
    }
    v4bf v; v[0]=(__bf16)k4.x; v[1]=(__bf16)k4.y; v[2]=(__bf16)k4.z; v[3]=(__bf16)k4.w;
    int slot = (d4 >> 1) ^ (jl & 7);
    *(v4bf*)&Klds[jl*64 + slot*8 + (d4 & 1)*4] = v;
  }
  // stage V transposed (f32 rows -> bf16 columns, swizzled)
  for (int e = tid; e < 224*16; e += 256) {
    int jl = e >> 4, d4 = e & 15;
    float4 v4 = make_float4(0.f,0.f,0.f,0.f);
    if (jl < 196)
      v4 = *(const float4*)&VS[((size_t)ns*196 + jl)*64 + d4*4];
    float vv[4] = {v4.x, v4.y, v4.z, v4.w};
#pragma unroll
    for (int c = 0; c < 4; ++c) {
      int d = d4*4 + c;
      int slot = (jl >> 3) ^ (d & 7);
      Vt[d*256 + slot*8 + (jl & 7)] = (__bf16)vv[c];
    }
  }
  __syncthreads();

  const int pb = wid * 512;   // per-wave P tile base (elements)

  for (int mt = wid; mt < 13; mt += 4) {
    // ---- Q A-fragments (gathered, global f32 -> bf16) ----
    const int iq = mt*16 + col;
    v8bf aQ0, aQ1;
    {
      float4 q0 = make_float4(0.f,0.f,0.f,0.f), q1=q0, q2=q0, q3=q0;
      if (iq < 196) {
        const float* qp = &QT[(((size_t)(hb*196 + iq))*16 + TT[iq])*64];
        q0 = *(const float4*)&qp[g*8];
        q1 = *(const float4*)&qp[g*8 + 4];
        q2 = *(const float4*)&qp[32 + g*8];
        q3 = *(const float4*)&qp[32 + g*8 + 4];
      }
      aQ0[0]=(__bf16)q0.x; aQ0[1]=(__bf16)q0.y; aQ0[2]=(__bf16)q0.z; aQ0[3]=(__bf16)q0.w;
      aQ0[4]=(__bf16)q1.x; aQ0[5]=(__bf16)q1.y; aQ0[6]=(__bf16)q1.z; aQ0[7]=(__bf16)q1.w;
      aQ1[0]=(__bf16)q2.x; aQ1[1]=(__bf16)q2.y; aQ1[2]=(__bf16)q2.z; aQ1[3]=(__bf16)q2.w;
      aQ1[4]=(__bf16)q3.x; aQ1[5]=(__bf16)q3.y; aQ1[6]=(__bf16)q3.z; aQ1[7]=(__bf16)q3.w;
    }

    // ---- QK^T: 13 N-tiles x (K=64 in two K-steps) ----
    f32x4 accP[13];
#pragma unroll
    for (int nt = 0; nt < 13; ++nt) { f32x4 z = {0.f,0.f,0.f,0.f}; accP[nt] = z; }
#pragma unroll
    for (int nt = 0; nt < 13; ++nt) {
      int j = nt*16 + col;
      v8bf b0 = *(v8bf*)&Klds[j*64 + ((0 + g) ^ (j & 7))*8];
      v8bf b1 = *(v8bf*)&Klds[j*64 + ((4 + g) ^ (j & 7))*8];
      accP[nt] = __builtin_amdgcn_mfma_f32_16x16x32_bf16(aQ0, b0, accP[nt], 0, 0, 0);
      accP[nt] = __builtin_amdgcn_mfma_f32_16x16x32_bf16(aQ1, b1, accP[nt], 0, 0, 0);
    }

    // ---- mask padded cols (j >= 196 lives in nt=12, col>=4) ----
    if (col >= 4) {
      accP[12][0] = -3.0e38f; accP[12][1] = -3.0e38f;
      accP[12][2] = -3.0e38f; accP[12][3] = -3.0e38f;
    }

    // ---- row softmax of S/8 across 13 frags + 16-lane column group ----
    float mxr[4], smr[4];
#pragma unroll
    for (int r = 0; r < 4; ++r) {
      float m = accP[0][r];
#pragma unroll
      for (int nt = 1; nt < 13; ++nt) m = fmaxf(m, accP[nt][r]);
      m = fmaxf(m, __shfl_xor(m, 1));
      m = fmaxf(m, __shfl_xor(m, 2));
      m = fmaxf(m, __shfl_xor(m, 4));
      m = fmaxf(m, __shfl_xor(m, 8));
      mxr[r] = m;
    }
#pragma unroll
    for (int r = 0; r < 4; ++r) {
      float s = 0.f;
#pragma unroll
      for (int nt = 0; nt < 13; ++nt) {
        float e = __expf((accP[nt][r] - mxr[r]) * 0.125f);
        accP[nt][r] = e; s += e;
      }
      s += __shfl_xor(s, 1);
      s += __shfl_xor(s, 2);
      s += __shfl_xor(s, 4);
      s += __shfl_xor(s, 8);
      smr[r] = 1.f / s;
    }
#pragma unroll
    for (int nt = 0; nt < 13; ++nt)
#pragma unroll
      for (int r = 0; r < 4; ++r) accP[nt][r] *= smr[r];

    // ---- write attn_s (f32) ----
#pragma unroll
    for (int nt = 0; nt < 13; ++nt) {
#pragma unroll
      for (int r = 0; r < 4; ++r) {
        int i = mt*16 + g*4 + r;
        int j = nt*16 + col;
        if (i < 196 && j < 196)
          attnOut[((size_t)ns*196 + i)*196 + j] = accP[nt][r];
      }
    }

    // ---- PV: O[16][64] = P[16][224] * V[224][64] via per-wave LDS P tile ----
    f32x4 oa[4];
#pragma unroll
    for (int n = 0; n < 4; ++n) { f32x4 z = {0.f,0.f,0.f,0.f}; oa[n] = z; }
#pragma unroll
    for (int ks = 0; ks < 7; ++ks) {
#pragma unroll
      for (int f = 0; f < 2; ++f) {
        const int fr = ks*2 + f;
#pragma unroll
        for (int r = 0; r < 4; ++r) {
          float pv = (fr < 13) ? accP[fr][r] : 0.f;
          int row = g*4 + r;
          int c = f*16 + col;
          Plds[pb + row*32 + (((c >> 3) ^ (row & 3)) << 3) + (c & 7)] = (__bf16)pv;
        }
      }
      v8bf ap = *(v8bf*)&Plds[pb + col*32 + ((g ^ (col & 3)) << 3)];
#pragma unroll
      for (int n = 0; n < 4; ++n) {
        int d = n*16 + col;
        v8bf bv = *(v8bf*)&Vt[d*256 + (((ks*4 + g) ^ (d & 7)) << 3)];
        oa[n] = __builtin_amdgcn_mfma_f32_16x16x32_bf16(ap, bv, oa[n], 0, 0, 0);
      }
    }

    // ---- write O ----
#pragma unroll
    for (int n = 0; n < 4; ++n) {
#pragma unroll
      for (int r = 0; r < 4; ++r) {
        int i = mt*16 + g*4 + r;
        if (i < 196)
          OS[((size_t)ns*196 + i)*64 + n*16 + col] = oa[n][r];
      }
    }
  }
}

// ---------------- K4: out projection ----------------
__global__ __launch_bounds__(256) void k4_outproj(
    const float* __restrict__ OS, const float* __restrict__ Wo,
    const float* __restrict__ bo, float* __restrict__ out)
{
  __shared__ float As[16][132];
  __shared__ float Bs[16][68];
  const int tid = threadIdx.x;
  const int tx = tid & 15;
  const int ty = tid >> 4;
  const int m0 = blockIdx.x * 128;
  const int n0 = blockIdx.y * 64;

  float acc[8][4];
#pragma unroll
  for (int i = 0; i < 8; ++i)
#pragma unroll
    for (int j = 0; j < 4; ++j) acc[i][j] = 0.f;

  for (int k0 = 0; k0 < 512; k0 += 16) {
    const int head = k0 >> 6;
#pragma unroll
    for (int r = 0; r < 2; ++r) {
      int e = tid + r * 256;
      int m = e >> 2, kq = e & 3;
      int mm = m0 + m;
      float4 a4 = make_float4(0.f,0.f,0.f,0.f);
      if (mm < MOUT) {
        int t1 = mm / 1568; int r1 = mm - t1*1568;
        int wh = r1 >> 3;    int b  = r1 & 7;
        int d = (k0 & 63) + kq*4;
        a4 = *(const float4*)&OS[((((size_t)(head*8 + b)*14) + t1)*196 + wh)*64 + d];
      }
      As[kq*4+0][m] = a4.x; As[kq*4+1][m] = a4.y;
      As[kq*4+2][m] = a4.z; As[kq*4+3][m] = a4.w;
    }
    {
      int n = tid >> 2, kq = tid & 3;
      const float4 b4 = *(const float4*)&Wo[(size_t)(n0 + n) * 512 + k0 + kq * 4];
      Bs[kq*4+0][n] = b4.x; Bs[kq*4+1][n] = b4.y;
      Bs[kq*4+2][n] = b4.z; Bs[kq*4+3][n] = b4.w;
    }
    __syncthreads();
#pragma unroll
    for (int kk = 0; kk < 16; ++kk) {
      const float4 a0 = *(const float4*)&As[kk][ty*8];
      const float4 a1 = *(const float4*)&As[kk][ty*8+4];
      const float4 b  = *(const float4*)&Bs[kk][tx*4];
      float am[8] = {a0.x,a0.y,a0.z,a0.w,a1.x,a1.y,a1.z,a1.w};
#pragma unroll
      for (int i = 0; i < 8; ++i) {
        acc[i][0] += am[i]*b.x; acc[i][1] += am[i]*b.y;
        acc[i][2] += am[i]*b.z; acc[i][3] += am[i]*b.w;
      }
    }
    __syncthreads();
  }

  const float b0 = bo[n0 + tx*4 + 0];
  const float b1 = bo[n0 + tx*4 + 1];
  const float b2 = bo[n0 + tx*4 + 2];
  const float b3 = bo[n0 + tx*4 + 3];
#pragma unroll
  for (int i = 0; i < 8; ++i) {
    int mm = m0 + ty*8 + i;
    if (mm < MOUT) {
      size_t off = 4096 + (size_t)(mm >> 3)*4096 + (size_t)(mm & 7)*512 + n0 + tx*4;
      float4 v = make_float4(acc[i][0]+b0, acc[i][1]+b1, acc[i][2]+b2, acc[i][3]+b3);
      *(float4*)&out[off] = v;
    }
  }
}

// ---------------- launch ----------------
extern "C" void kernel_launch(void* const* d_in, const int* in_sizes, int n_in,
                              void* d_out, int out_size, void* d_ws, size_t ws_size,
                              hipStream_t stream) {
  const float* q  = (const float*)d_in[0];
  const float* Wi = (const float*)d_in[3];
  const float* bi = (const float*)d_in[4];
  const float* Wo = (const float*)d_in[5];
  const float* bo = (const float*)d_in[6];

  float* out     = (float*)d_out;
  float* attnOut = out + OUT0_SZ;
  float* idxOut  = out + OUT0_SZ + ATTN_SZ;

  float* ws = (float*)d_ws;
  float* QT = ws;
  float* KT = QT + SZ_T;
  float* VT = KT + SZ_T;
  float* VS = VT + SZ_T;
  float* OS = VS + SZ_S;
  int* IDXW = (int*)(OS + SZ_S);

  k0_cls<<<4, 256, 0, stream>>>(q, out);
  k1_qkv<<<dim3(196, 24), 256, 0, stream>>>(q, Wi, bi, QT, KT, VT);
  k2_temporal<<<NB, 64, 0, stream>>>(QT, KT, VT, VS, IDXW, idxOut);
  k3_spatial<<<NS, 256, 0, stream>>>(QT, KT, VS, IDXW, attnOut, OS);
  k4_outproj<<<dim3(172, 8), 256, 0, stream>>>(OS, Wo, bo, out);
}